// Round 14
// baseline (184.765 us; speedup 1.0000x reference)
//
#include <hip/hip_runtime.h>
#include <math.h>

#define IN_F 128
#define C1 32            // 2 heads * 16
#define NEG 0.2f
#define BSZ 128          // nodes per fine bucket (dst>>7)
#define CAP 2560         // edge-slot capacity per bucket (mean ~2175, +8 sigma)
#define EPB 2048         // edges per multisplit block
#define TPW 2            // 16-node tiles per wave in proj branch

typedef _Float16 h16;
typedef _Float16 h16x2 __attribute__((ext_vector_type(2)));
typedef _Float16 h16x4 __attribute__((ext_vector_type(4)));
typedef _Float16 h16x8 __attribute__((ext_vector_type(8)));
typedef float f32x4 __attribute__((ext_vector_type(4)));

__device__ __forceinline__ float leaky(float x) { return x >= 0.f ? x : NEG * x; }

// ------- fat kernel: proj1 (blocks 0..nproj-1) | mscat (rest) -----------
// proj: MFMA 16x16x32_f16 (R10-proven), no LDS.
// mscat: LDS-histogram multisplit; d cached in LDS (8 KB), s re-read fresh
//        (coalesced, first touch) in scatter phase. 16 KB total LDS.
__global__ __launch_bounds__(256)
void k_fat(const float* __restrict__ x, const float* __restrict__ W1,
           const float* __restrict__ a_s, const float* __restrict__ a_d,
           h16* __restrict__ h1h, float* __restrict__ as1,
           float* __restrict__ ad1, int N,
           const int* __restrict__ ei, int E, int ET, int nbk,
           int* __restrict__ bcnt, int* __restrict__ ebuf, int nproj) {
    __shared__ int smem[4096];                   // 16 KB (mscat branch only)
    int t = threadIdx.x;
    if ((int)blockIdx.x < nproj) {
        // ---------------- MFMA projection branch ----------------
        int wid = t >> 6, lane = t & 63;
        int q = lane >> 4, r = lane & 15;
        h16x8 Bf[2][4];
        #pragma unroll
        for (int ct = 0; ct < 2; ++ct)
            #pragma unroll
            for (int kc = 0; kc < 4; ++kc)
                #pragma unroll
                for (int j = 0; j < 8; ++j)
                    Bf[ct][kc][j] = (h16)W1[(kc * 32 + q * 8 + j) * C1 + ct * 16 + r];
        float a_s0 = a_s[r], a_s1v = a_s[16 + r];
        float a_d0 = a_d[r], a_d1v = a_d[16 + r];
        #pragma unroll
        for (int tt = 0; tt < TPW; ++tt) {
            int tile = (blockIdx.x * 4 + wid) * TPW + tt;
            int m0 = tile << 4;
            if (m0 >= N) break;
            int row = m0 + r; if (row >= N) row = N - 1;
            const float* xr = x + (size_t)row * IN_F + q * 8;
            f32x4 acc0 = {0.f, 0.f, 0.f, 0.f};
            f32x4 acc1 = {0.f, 0.f, 0.f, 0.f};
            #pragma unroll
            for (int kc = 0; kc < 4; ++kc) {
                float4 xa = *(const float4*)(xr + kc * 32);
                float4 xb = *(const float4*)(xr + kc * 32 + 4);
                h16x8 A;
                A[0] = (h16)xa.x; A[1] = (h16)xa.y; A[2] = (h16)xa.z; A[3] = (h16)xa.w;
                A[4] = (h16)xb.x; A[5] = (h16)xb.y; A[6] = (h16)xb.z; A[7] = (h16)xb.w;
                acc0 = __builtin_amdgcn_mfma_f32_16x16x32_f16(A, Bf[0][kc], acc0, 0, 0, 0);
                acc1 = __builtin_amdgcn_mfma_f32_16x16x32_f16(A, Bf[1][kc], acc1, 0, 0, 0);
            }
            #pragma unroll
            for (int reg = 0; reg < 4; ++reg) {
                int node = m0 + q * 4 + reg;
                bool vld = node < N;
                float h0 = acc0[reg], h1 = acc1[reg];
                if (vld) {
                    h1h[(size_t)node * C1 + r]      = (h16)h0;
                    h1h[(size_t)node * C1 + 16 + r] = (h16)h1;
                }
                float s0 = h0 * a_s0, s1 = h1 * a_s1v;
                float d0 = h0 * a_d0, d1 = h1 * a_d1v;
                s0 += __shfl_xor(s0, 1); s0 += __shfl_xor(s0, 2); s0 += __shfl_xor(s0, 4); s0 += __shfl_xor(s0, 8);
                s1 += __shfl_xor(s1, 1); s1 += __shfl_xor(s1, 2); s1 += __shfl_xor(s1, 4); s1 += __shfl_xor(s1, 8);
                d0 += __shfl_xor(d0, 1); d0 += __shfl_xor(d0, 2); d0 += __shfl_xor(d0, 4); d0 += __shfl_xor(d0, 8);
                d1 += __shfl_xor(d1, 1); d1 += __shfl_xor(d1, 2); d1 += __shfl_xor(d1, 4); d1 += __shfl_xor(d1, 8);
                if (vld && r == 0) {
                    *(float2*)&as1[node * 2] = make_float2(s0, s1);
                    *(float2*)&ad1[node * 2] = make_float2(d0, d1);
                }
            }
        }
    } else {
        // ---------------- multisplit branch ----------------
        int* hist   = smem;                     // 1024
        int* lcur   = hist + 1024;              // 1024
        int* dcache = lcur + 1024;              // EPB ints = 8 KB
        int bid = blockIdx.x - nproj;
        hist[t] = 0; hist[t + 256] = 0; hist[t + 512] = 0; hist[t + 768] = 0;
        __syncthreads();
        int i0 = bid * EPB, i1 = min(ET, i0 + EPB);
        for (int i = i0 + t; i < i1; i += 256) {
            int d = (i < E) ? ei[E + i] : i - E;
            dcache[i - i0] = d;
            atomicAdd(&hist[d >> 7], 1);
        }
        __syncthreads();
        for (int b = t; b < nbk; b += 256) {
            int h = hist[b];
            int base = h ? atomicAdd(&bcnt[b], h) : 0;
            lcur[b] = b * CAP + base;
        }
        __syncthreads();
        for (int i = i0 + t; i < i1; i += 256) {
            int s = (i < E) ? ei[i] : i - E;       // fresh coalesced read
            int d = dcache[i - i0];
            int bkt = d >> 7;
            int pos = atomicAdd(&lcur[bkt], 1);
            if (pos < (bkt + 1) * CAP)             // safety net vs overflow
                ebuf[pos] = (s << 7) | (d & 127);
        }
    }
}

// ---- fused bucket CSR + layer-1 aggregation + epilogue (R13-proven) ----
__global__ __launch_bounds__(512)
void k_bagg(const int* __restrict__ bcnt, const int* __restrict__ ebuf,
            int N, int nbk, int ET,
            const float* __restrict__ as1, const float* __restrict__ ad1,
            const float* __restrict__ b1, const float* __restrict__ W2,
            const h16* __restrict__ h1h, int* __restrict__ off,
            int* __restrict__ csr1, float* __restrict__ p2) {
    __shared__ int2 elist[CAP];          // 20.5 KB sorted (src, fp16 w0|w1)
    __shared__ int deg[BSZ], sst[BSZ], cur[BSZ];
    __shared__ float adl[BSZ * 2];
    __shared__ int red[8];
    int b = blockIdx.x, t = threadIdx.x;
    int cnt = min(bcnt[b], CAP);
    int ebase = b * CAP;
    int n0 = b * BSZ;
    // fbase = sum_{k<b} min(bcnt[k],CAP)
    int part = 0;
    for (int k = t; k < b; k += 512) part += min(bcnt[k], CAP);
    part += __shfl_xor(part, 1);  part += __shfl_xor(part, 2);
    part += __shfl_xor(part, 4);  part += __shfl_xor(part, 8);
    part += __shfl_xor(part, 16); part += __shfl_xor(part, 32);
    if ((t & 63) == 0) red[t >> 6] = part;
    if (t < BSZ) {
        deg[t] = 0;
        int n = n0 + t;
        float2 v = (n < N) ? ((const float2*)ad1)[n] : make_float2(0.f, 0.f);
        adl[t * 2] = v.x; adl[t * 2 + 1] = v.y;
    }
    __syncthreads();
    int fbase = red[0] + red[1] + red[2] + red[3] + red[4] + red[5] + red[6] + red[7];
    if (b == nbk - 1 && t == 0) off[N] = ET;
    // histogram
    for (int i = t; i < cnt; i += 512)
        atomicAdd(&deg[ebuf[ebase + i] & 127], 1);
    __syncthreads();
    int v = (t < BSZ) ? deg[t] : 0;
    __syncthreads();
    for (int o = 1; o < BSZ; o <<= 1) {
        int xv = (t >= o && t < BSZ) ? deg[t - o] : 0;
        __syncthreads();
        if (t < BSZ) deg[t] += xv;                 // deg -> inclusive scan
        __syncthreads();
    }
    if (t < BSZ) {
        int excl = deg[t] - v;
        sst[t] = excl; cur[t] = excl;
        if (n0 + t < N) off[n0 + t] = fbase + excl;
    }
    __syncthreads();
    // weighted placement into sorted LDS list + slim global csr1
    for (int i = t; i < cnt; i += 512) {
        int e = ebuf[ebase + i];
        int dl = e & 127, s = e >> 7;
        float2 asv = ((const float2*)as1)[s];      // L2-resident 8B gather
        float w0 = __expf(leaky(asv.x + adl[dl * 2 + 0]));
        float w1 = __expf(leaky(asv.y + adl[dl * 2 + 1]));
        h16x2 wp = { (h16)w0, (h16)w1 };
        int p = atomicAdd(&cur[dl], 1);
        int2 rec; rec.x = s; rec.y = *(int*)&wp;
        elist[p] = rec;
        csr1[fbase + p] = s;
    }
    __syncthreads();
    // node-parallel aggregation: 128 nodes in ONE pass, 4 lanes/node
    int l = t & 3, dl = t >> 2, c0 = l * 8, head = l >> 1;
    int node = n0 + dl;
    if (node >= N) return;
    int j0 = sst[dl], j1 = deg[dl];                // [start, inclusive-end)
    float den = 0.f;
    float acc[8];
    #pragma unroll
    for (int c = 0; c < 8; ++c) acc[c] = 0.f;
    for (int j = j0; j < j1; j += 4) {
        #pragma unroll
        for (int k = 0; k < 4; ++k) {
            int jj = j + k;
            bool valid = jj < j1;
            jj = valid ? jj : j0;
            int2 e = elist[jj];                    // LDS read
            int s = e.x;
            h16x2 wv = *(h16x2*)&e.y;
            float w = valid ? (float)(head ? wv.y : wv.x) : 0.f;
            h16x8 hv = *(const h16x8*)(h1h + ((size_t)s << 5) + c0);  // 16B gather
            den += w;
            #pragma unroll
            for (int c = 0; c < 8; ++c) acc[c] = fmaf(w, (float)hv[c], acc[c]);
        }
    }
    float inv = 1.f / (den + 1e-16f);
    float val = 0.f;
    #pragma unroll
    for (int c = 0; c < 8; ++c) {
        float o = acc[c] * inv + b1[c0 + c];
        o = o > 0.f ? o : expm1f(o);               // ELU
        val = fmaf(o, W2[c0 + c], val);
    }
    val += __shfl_xor(val, 1); val += __shfl_xor(val, 2);
    if (l == 0) p2[node] = val;
}

// ---- layer-2: 4 lanes/node, 2-unroll (R13-proven) ----------------------
__global__ __launch_bounds__(256)
void k_l2(const int* __restrict__ off, const int* __restrict__ csr1,
          const float* __restrict__ p2, const float* __restrict__ as2,
          const float* __restrict__ ad2, const float* __restrict__ b2,
          float* __restrict__ out, int N) {
    int t = threadIdx.x;
    int node = blockIdx.x * 64 + (t >> 2);
    if (node >= N) return;
    int l = t & 3;
    float A = as2[0];
    float Bc = ad2[0] * p2[node];
    float den = 0.f, num = 0.f;
    int j0 = off[node], j1 = off[node + 1];
    for (int j = j0 + l; j < j1; j += 8) {
        int s0 = csr1[j];
        int jb = j + 4;
        bool vb = jb < j1;
        int s1 = csr1[vb ? jb : j];
        float ps0 = p2[s0], ps1 = p2[s1];          // L2-resident 4B gathers
        float w0 = __expf(leaky(fmaf(ps0, A, Bc)));
        float w1 = vb ? __expf(leaky(fmaf(ps1, A, Bc))) : 0.f;
        den += w0 + w1;
        num = fmaf(w0, ps0, fmaf(w1, ps1, num));
    }
    den += __shfl_xor(den, 1); den += __shfl_xor(den, 2);
    num += __shfl_xor(num, 1); num += __shfl_xor(num, 2);
    if (l == 0) out[node] = num / (den + 1e-16f) + b2[0];
}

extern "C" void kernel_launch(void* const* d_in, const int* in_sizes, int n_in,
                              void* d_out, int out_size, void* d_ws, size_t ws_size,
                              hipStream_t stream) {
    const float* x    = (const float*)d_in[0];
    const int*   ei   = (const int*)d_in[1];
    const float* W1   = (const float*)d_in[2];
    const float* a_s1 = (const float*)d_in[3];
    const float* a_d1 = (const float*)d_in[4];
    const float* b1   = (const float*)d_in[5];
    const float* W2   = (const float*)d_in[6];
    const float* a_s2 = (const float*)d_in[7];
    const float* a_d2 = (const float*)d_in[8];
    const float* b2   = (const float*)d_in[9];
    float* out = (float*)d_out;

    const int N  = in_sizes[0] / IN_F;   // 100000
    const int E  = in_sizes[1] / 2;      // 1600000
    const int ET = E + N;
    const int nbk = (N + BSZ - 1) / BSZ;              // 782 buckets

    // workspace layout (~22 MB; only bcnt needs zeroing)
    float* w   = (float*)d_ws;
    float* as1 = w; w += (size_t)2 * N;
    float* ad1 = w; w += (size_t)2 * N;
    float* p2  = w; w += (size_t)N;
    h16* h1h   = (h16*)w;                // 32*N halves
    w += (size_t)16 * N;
    int* iw     = (int*)w;
    int* bcnt   = iw; iw += 1024;
    int* off    = iw; iw += (N + 1);
    int* csr1   = iw; iw += ET;
    int* ebuf   = iw; iw += (size_t)nbk * CAP;

    const int B = 256;
    const int ntile = (N + 15) / 16;                  // 6250 16-node tiles
    const int nproj = (ntile + 4 * TPW - 1) / (4 * TPW);  // 782 proj blocks
    const int nblkA = (ET + EPB - 1) / EPB;           // 831 multisplit blocks

    hipMemsetAsync(bcnt, 0, 1024 * sizeof(int), stream);
    k_fat <<<nproj + nblkA, B, 0, stream>>>(x, W1, a_s1, a_d1, h1h, as1, ad1, N,
                                            ei, E, ET, nbk, bcnt, ebuf, nproj);
    k_bagg<<<nbk, 512, 0, stream>>>(bcnt, ebuf, N, nbk, ET, as1, ad1, b1, W2,
                                    h1h, off, csr1, p2);
    k_l2  <<<(N + 63) / 64, B, 0, stream>>>(off, csr1, p2, a_s2, a_d2, b2, out, N);
}

// Round 15
// 182.391 us; speedup vs baseline: 1.0130x; 1.0130x over previous
//
#include <hip/hip_runtime.h>
#include <math.h>

#define IN_F 128
#define C1 32            // 2 heads * 16
#define NEG 0.2f
#define BSZ 128          // nodes per fine bucket (dst>>7)
#define CAP 2560         // edge-slot capacity per bucket (mean ~2175, +8 sigma)
#define EPB 2048         // edges per multisplit block
#define TPW 2            // 16-node tiles per wave in proj branch

typedef _Float16 h16;
typedef _Float16 h16x2 __attribute__((ext_vector_type(2)));
typedef _Float16 h16x4 __attribute__((ext_vector_type(4)));
typedef _Float16 h16x8 __attribute__((ext_vector_type(8)));
typedef float f32x4 __attribute__((ext_vector_type(4)));

__device__ __forceinline__ float leaky(float x) { return x >= 0.f ? x : NEG * x; }

// ------- fat kernel: proj1 (blocks 0..nproj-1) | mscat (rest) -----------
// proj: MFMA 16x16x32_f16 (R10-proven), no LDS.
// mscat: R12-proven — full int2 ecache (16 KB); ei read exactly once.
__global__ __launch_bounds__(256)
void k_fat(const float* __restrict__ x, const float* __restrict__ W1,
           const float* __restrict__ a_s, const float* __restrict__ a_d,
           h16* __restrict__ h1h, float* __restrict__ as1,
           float* __restrict__ ad1, int N,
           const int* __restrict__ ei, int E, int ET, int nbk,
           int* __restrict__ bcnt, int* __restrict__ ebuf, int nproj) {
    __shared__ int smem[6144];                   // 24 KB (mscat branch only)
    int t = threadIdx.x;
    if ((int)blockIdx.x < nproj) {
        // ---------------- MFMA projection branch ----------------
        int wid = t >> 6, lane = t & 63;
        int q = lane >> 4, r = lane & 15;
        h16x8 Bf[2][4];
        #pragma unroll
        for (int ct = 0; ct < 2; ++ct)
            #pragma unroll
            for (int kc = 0; kc < 4; ++kc)
                #pragma unroll
                for (int j = 0; j < 8; ++j)
                    Bf[ct][kc][j] = (h16)W1[(kc * 32 + q * 8 + j) * C1 + ct * 16 + r];
        float a_s0 = a_s[r], a_s1v = a_s[16 + r];
        float a_d0 = a_d[r], a_d1v = a_d[16 + r];
        #pragma unroll
        for (int tt = 0; tt < TPW; ++tt) {
            int tile = (blockIdx.x * 4 + wid) * TPW + tt;
            int m0 = tile << 4;
            if (m0 >= N) break;
            int row = m0 + r; if (row >= N) row = N - 1;
            const float* xr = x + (size_t)row * IN_F + q * 8;
            f32x4 acc0 = {0.f, 0.f, 0.f, 0.f};
            f32x4 acc1 = {0.f, 0.f, 0.f, 0.f};
            #pragma unroll
            for (int kc = 0; kc < 4; ++kc) {
                float4 xa = *(const float4*)(xr + kc * 32);
                float4 xb = *(const float4*)(xr + kc * 32 + 4);
                h16x8 A;
                A[0] = (h16)xa.x; A[1] = (h16)xa.y; A[2] = (h16)xa.z; A[3] = (h16)xa.w;
                A[4] = (h16)xb.x; A[5] = (h16)xb.y; A[6] = (h16)xb.z; A[7] = (h16)xb.w;
                acc0 = __builtin_amdgcn_mfma_f32_16x16x32_f16(A, Bf[0][kc], acc0, 0, 0, 0);
                acc1 = __builtin_amdgcn_mfma_f32_16x16x32_f16(A, Bf[1][kc], acc1, 0, 0, 0);
            }
            #pragma unroll
            for (int reg = 0; reg < 4; ++reg) {
                int node = m0 + q * 4 + reg;
                bool vld = node < N;
                float h0 = acc0[reg], h1 = acc1[reg];
                if (vld) {
                    h1h[(size_t)node * C1 + r]      = (h16)h0;
                    h1h[(size_t)node * C1 + 16 + r] = (h16)h1;
                }
                float s0 = h0 * a_s0, s1 = h1 * a_s1v;
                float d0 = h0 * a_d0, d1 = h1 * a_d1v;
                s0 += __shfl_xor(s0, 1); s0 += __shfl_xor(s0, 2); s0 += __shfl_xor(s0, 4); s0 += __shfl_xor(s0, 8);
                s1 += __shfl_xor(s1, 1); s1 += __shfl_xor(s1, 2); s1 += __shfl_xor(s1, 4); s1 += __shfl_xor(s1, 8);
                d0 += __shfl_xor(d0, 1); d0 += __shfl_xor(d0, 2); d0 += __shfl_xor(d0, 4); d0 += __shfl_xor(d0, 8);
                d1 += __shfl_xor(d1, 1); d1 += __shfl_xor(d1, 2); d1 += __shfl_xor(d1, 4); d1 += __shfl_xor(d1, 8);
                if (vld && r == 0) {
                    *(float2*)&as1[node * 2] = make_float2(s0, s1);
                    *(float2*)&ad1[node * 2] = make_float2(d0, d1);
                }
            }
        }
    } else {
        // ---------------- multisplit branch (R12-proven) ----------------
        int* hist = smem;                       // 1024
        int* lcur = hist + 1024;                // 1024
        int2* ecache = (int2*)(lcur + 1024);    // EPB int2 = 16 KB
        int bid = blockIdx.x - nproj;
        hist[t] = 0; hist[t + 256] = 0; hist[t + 512] = 0; hist[t + 768] = 0;
        __syncthreads();
        int i0 = bid * EPB, i1 = min(ET, i0 + EPB);
        for (int i = i0 + t; i < i1; i += 256) {
            int s, d;
            if (i < E) { s = ei[i]; d = ei[E + i]; } else { s = d = i - E; }
            ecache[i - i0] = make_int2(s, d);
            atomicAdd(&hist[d >> 7], 1);
        }
        __syncthreads();
        for (int b = t; b < nbk; b += 256) {
            int h = hist[b];
            int base = h ? atomicAdd(&bcnt[b], h) : 0;
            lcur[b] = b * CAP + base;
        }
        __syncthreads();
        for (int i = i0 + t; i < i1; i += 256) {
            int2 e = ecache[i - i0];
            int bkt = e.y >> 7;
            int pos = atomicAdd(&lcur[bkt], 1);
            if (pos < (bkt + 1) * CAP)             // safety net vs overflow
                ebuf[pos] = (e.x << 7) | (e.y & 127);
        }
    }
}

// ---- fused bucket CSR + layer-1 aggregation + epilogue (R13-proven) ----
__global__ __launch_bounds__(512)
void k_bagg(const int* __restrict__ bcnt, const int* __restrict__ ebuf,
            int N, int nbk, int ET,
            const float* __restrict__ as1, const float* __restrict__ ad1,
            const float* __restrict__ b1, const float* __restrict__ W2,
            const h16* __restrict__ h1h, int* __restrict__ off,
            int* __restrict__ csr1, float* __restrict__ p2) {
    __shared__ int2 elist[CAP];          // 20.5 KB sorted (src, fp16 w0|w1)
    __shared__ int deg[BSZ], sst[BSZ], cur[BSZ];
    __shared__ float adl[BSZ * 2];
    __shared__ int red[8];
    int b = blockIdx.x, t = threadIdx.x;
    int cnt = min(bcnt[b], CAP);
    int ebase = b * CAP;
    int n0 = b * BSZ;
    // fbase = sum_{k<b} min(bcnt[k],CAP)
    int part = 0;
    for (int k = t; k < b; k += 512) part += min(bcnt[k], CAP);
    part += __shfl_xor(part, 1);  part += __shfl_xor(part, 2);
    part += __shfl_xor(part, 4);  part += __shfl_xor(part, 8);
    part += __shfl_xor(part, 16); part += __shfl_xor(part, 32);
    if ((t & 63) == 0) red[t >> 6] = part;
    if (t < BSZ) {
        deg[t] = 0;
        int n = n0 + t;
        float2 v = (n < N) ? ((const float2*)ad1)[n] : make_float2(0.f, 0.f);
        adl[t * 2] = v.x; adl[t * 2 + 1] = v.y;
    }
    __syncthreads();
    int fbase = red[0] + red[1] + red[2] + red[3] + red[4] + red[5] + red[6] + red[7];
    if (b == nbk - 1 && t == 0) off[N] = ET;
    // histogram
    for (int i = t; i < cnt; i += 512)
        atomicAdd(&deg[ebuf[ebase + i] & 127], 1);
    __syncthreads();
    int v = (t < BSZ) ? deg[t] : 0;
    __syncthreads();
    for (int o = 1; o < BSZ; o <<= 1) {
        int xv = (t >= o && t < BSZ) ? deg[t - o] : 0;
        __syncthreads();
        if (t < BSZ) deg[t] += xv;                 // deg -> inclusive scan
        __syncthreads();
    }
    if (t < BSZ) {
        int excl = deg[t] - v;
        sst[t] = excl; cur[t] = excl;
        if (n0 + t < N) off[n0 + t] = fbase + excl;
    }
    __syncthreads();
    // weighted placement into sorted LDS list + slim global csr1
    for (int i = t; i < cnt; i += 512) {
        int e = ebuf[ebase + i];
        int dl = e & 127, s = e >> 7;
        float2 asv = ((const float2*)as1)[s];      // L2-resident 8B gather
        float w0 = __expf(leaky(asv.x + adl[dl * 2 + 0]));
        float w1 = __expf(leaky(asv.y + adl[dl * 2 + 1]));
        h16x2 wp = { (h16)w0, (h16)w1 };
        int p = atomicAdd(&cur[dl], 1);
        int2 rec; rec.x = s; rec.y = *(int*)&wp;
        elist[p] = rec;
        csr1[fbase + p] = s;
    }
    __syncthreads();
    // node-parallel aggregation: 128 nodes in ONE pass, 4 lanes/node
    int l = t & 3, dl = t >> 2, c0 = l * 8, head = l >> 1;
    int node = n0 + dl;
    if (node >= N) return;
    int j0 = sst[dl], j1 = deg[dl];                // [start, inclusive-end)
    float den = 0.f;
    float acc[8];
    #pragma unroll
    for (int c = 0; c < 8; ++c) acc[c] = 0.f;
    for (int j = j0; j < j1; j += 4) {
        #pragma unroll
        for (int k = 0; k < 4; ++k) {
            int jj = j + k;
            bool valid = jj < j1;
            jj = valid ? jj : j0;
            int2 e = elist[jj];                    // LDS read
            int s = e.x;
            h16x2 wv = *(h16x2*)&e.y;
            float w = valid ? (float)(head ? wv.y : wv.x) : 0.f;
            h16x8 hv = *(const h16x8*)(h1h + ((size_t)s << 5) + c0);  // 16B gather
            den += w;
            #pragma unroll
            for (int c = 0; c < 8; ++c) acc[c] = fmaf(w, (float)hv[c], acc[c]);
        }
    }
    float inv = 1.f / (den + 1e-16f);
    float val = 0.f;
    #pragma unroll
    for (int c = 0; c < 8; ++c) {
        float o = acc[c] * inv + b1[c0 + c];
        o = o > 0.f ? o : expm1f(o);               // ELU
        val = fmaf(o, W2[c0 + c], val);
    }
    val += __shfl_xor(val, 1); val += __shfl_xor(val, 2);
    if (l == 0) p2[node] = val;
}

// ---- layer-2: 4 lanes/node, 2-unroll (R13-proven) ----------------------
__global__ __launch_bounds__(256)
void k_l2(const int* __restrict__ off, const int* __restrict__ csr1,
          const float* __restrict__ p2, const float* __restrict__ as2,
          const float* __restrict__ ad2, const float* __restrict__ b2,
          float* __restrict__ out, int N) {
    int t = threadIdx.x;
    int node = blockIdx.x * 64 + (t >> 2);
    if (node >= N) return;
    int l = t & 3;
    float A = as2[0];
    float Bc = ad2[0] * p2[node];
    float den = 0.f, num = 0.f;
    int j0 = off[node], j1 = off[node + 1];
    for (int j = j0 + l; j < j1; j += 8) {
        int s0 = csr1[j];
        int jb = j + 4;
        bool vb = jb < j1;
        int s1 = csr1[vb ? jb : j];
        float ps0 = p2[s0], ps1 = p2[s1];          // L2-resident 4B gathers
        float w0 = __expf(leaky(fmaf(ps0, A, Bc)));
        float w1 = vb ? __expf(leaky(fmaf(ps1, A, Bc))) : 0.f;
        den += w0 + w1;
        num = fmaf(w0, ps0, fmaf(w1, ps1, num));
    }
    den += __shfl_xor(den, 1); den += __shfl_xor(den, 2);
    num += __shfl_xor(num, 1); num += __shfl_xor(num, 2);
    if (l == 0) out[node] = num / (den + 1e-16f) + b2[0];
}

extern "C" void kernel_launch(void* const* d_in, const int* in_sizes, int n_in,
                              void* d_out, int out_size, void* d_ws, size_t ws_size,
                              hipStream_t stream) {
    const float* x    = (const float*)d_in[0];
    const int*   ei   = (const int*)d_in[1];
    const float* W1   = (const float*)d_in[2];
    const float* a_s1 = (const float*)d_in[3];
    const float* a_d1 = (const float*)d_in[4];
    const float* b1   = (const float*)d_in[5];
    const float* W2   = (const float*)d_in[6];
    const float* a_s2 = (const float*)d_in[7];
    const float* a_d2 = (const float*)d_in[8];
    const float* b2   = (const float*)d_in[9];
    float* out = (float*)d_out;

    const int N  = in_sizes[0] / IN_F;   // 100000
    const int E  = in_sizes[1] / 2;      // 1600000
    const int ET = E + N;
    const int nbk = (N + BSZ - 1) / BSZ;              // 782 buckets

    // workspace layout (~22 MB; only bcnt needs zeroing)
    float* w   = (float*)d_ws;
    float* as1 = w; w += (size_t)2 * N;
    float* ad1 = w; w += (size_t)2 * N;
    float* p2  = w; w += (size_t)N;
    h16* h1h   = (h16*)w;                // 32*N halves
    w += (size_t)16 * N;
    int* iw     = (int*)w;
    int* bcnt   = iw; iw += 1024;
    int* off    = iw; iw += (N + 1);
    int* csr1   = iw; iw += ET;
    int* ebuf   = iw; iw += (size_t)nbk * CAP;

    const int B = 256;
    const int ntile = (N + 15) / 16;                  // 6250 16-node tiles
    const int nproj = (ntile + 4 * TPW - 1) / (4 * TPW);  // 782 proj blocks
    const int nblkA = (ET + EPB - 1) / EPB;           // 831 multisplit blocks

    hipMemsetAsync(bcnt, 0, 1024 * sizeof(int), stream);
    k_fat <<<nproj + nblkA, B, 0, stream>>>(x, W1, a_s1, a_d1, h1h, as1, ad1, N,
                                            ei, E, ET, nbk, bcnt, ebuf, nproj);
    k_bagg<<<nbk, 512, 0, stream>>>(bcnt, ebuf, N, nbk, ET, as1, ad1, b1, W2,
                                    h1h, off, csr1, p2);
    k_l2  <<<(N + 63) / 64, B, 0, stream>>>(off, csr1, p2, a_s2, a_d2, b2, out, N);
}